// Round 4
// baseline (720.742 us; speedup 1.0000x reference)
//
#include <hip/hip_runtime.h>
#include <math.h>

#define Bb 2
#define Nn 512
#define RR 1024
#define HH 8
#define PROJC 704
#define CONCATC 1280

#define SCALAR_SCALE 0.14433756729740643f
#define POINT_SCALE  0.13608276348795434f
#define PAIR_SCALE   0.5773502691896258f

typedef __attribute__((ext_vector_type(4))) float f32x4;
typedef __attribute__((ext_vector_type(8))) short short8;
typedef __attribute__((ext_vector_type(8))) unsigned short ush8;

__device__ __forceinline__ float wred_sum(float v) {
#pragma unroll
  for (int o = 1; o < 64; o <<= 1) v += __shfl_xor(v, o);
  return v;
}
__device__ __forceinline__ unsigned short f2bf(float f) {
  unsigned int u = __float_as_uint(f);
  unsigned int r = (u + 0x7FFFu + ((u >> 16) & 1u)) >> 16;
  return (unsigned short)r;
}

// ---------------- 1. gather + transpose + cvt Wcat_t bf16 [704][512]
__global__ __launch_bounds__(256) void gather_wcat_t(
    const float* __restrict__ Wqs, const float* __restrict__ Wks,
    const float* __restrict__ Wvs, const float* __restrict__ Wqp,
    const float* __restrict__ Wkp, const float* __restrict__ Wvp,
    unsigned short* __restrict__ Wt) {
  int c = blockIdx.x;
  for (int k = threadIdx.x; k < 512; k += 256) {
    float val = 0.f;
    if (c < 128)      val = Wqs[k * 128 + c];
    else if (c < 256) val = Wks[k * 128 + c - 128];
    else if (c < 384) val = Wvs[k * 128 + c - 256];
    else if (c < 480) val = Wqp[k * 96 + c - 384];
    else if (c < 576) val = Wkp[k * 96 + c - 480];
    else if (c < 672) val = Wvp[k * 96 + c - 576];
    Wt[(size_t)c * 512 + k] = f2bf(val);
  }
}

// ---------------- 2. transpose+cvt 4 weights: f32 [K][512] -> bf16 [512][K]
__global__ __launch_bounds__(256) void transp_cvt4(
    const float* __restrict__ w0, const float* __restrict__ w1,
    const float* __restrict__ w2, const float* __restrict__ w3,
    unsigned short* __restrict__ o0, unsigned short* __restrict__ o1,
    unsigned short* __restrict__ o2, unsigned short* __restrict__ o3) {
  int z = blockIdx.z;
  const float* in = (z == 0) ? w0 : (z == 1) ? w1 : (z == 2) ? w2 : w3;
  unsigned short* out = (z == 0) ? o0 : (z == 1) ? o1 : (z == 2) ? o2 : o3;
  int K = (z == 0) ? 1280 : 512;
  int k0 = blockIdx.y * 32, n0 = blockIdx.x * 32;
  if (k0 >= K) return;
  __shared__ float tile[32][33];
  int t = threadIdx.x;
  int r = t >> 3, cq = (t & 7) * 4;
  float4 v = *(const float4*)&in[(size_t)(k0 + r) * 512 + n0 + cq];
  tile[r][cq] = v.x; tile[r][cq + 1] = v.y; tile[r][cq + 2] = v.z; tile[r][cq + 3] = v.w;
  __syncthreads();
  ushort4 o4;
  o4.x = f2bf(tile[cq + 0][r]);
  o4.y = f2bf(tile[cq + 1][r]);
  o4.z = f2bf(tile[cq + 2][r]);
  o4.w = f2bf(tile[cq + 3][r]);
  *(ushort4*)&out[(size_t)(n0 + r) * K + k0 + cq] = o4;
}

// ---------------- 3. bf16 MFMA GEMM (64x64 tile)
__global__ __launch_bounds__(256) void gemm_bf16(
    const float* __restrict__ A, int lda,
    const unsigned short* __restrict__ Bt, int K,
    float* __restrict__ C, int ldc,
    const float* __restrict__ bias, int relu) {
  __shared__ unsigned short As[64][72];
  __shared__ unsigned short Bs[64][72];
  int t = threadIdx.x;
  int lane = t & 63, w = t >> 6;
  int wr = (w >> 1) * 32, wc = (w & 1) * 32;
  int fr = lane & 15, fk = (lane >> 4) * 8;
  f32x4 zero = {0.f, 0.f, 0.f, 0.f};
  f32x4 acc00 = zero, acc01 = zero, acc10 = zero, acc11 = zero;
  int sr = t >> 2, sc = (t & 3) * 16;
  int bm = blockIdx.y * 64, bn = blockIdx.x * 64;
  const float* Arow = A + (size_t)(bm + sr) * lda + sc;
  const unsigned short* Brow = Bt + (size_t)(bn + sr) * K + sc;
  for (int k0 = 0; k0 < K; k0 += 64) {
    float4 a0 = *(const float4*)(Arow + k0);
    float4 a1 = *(const float4*)(Arow + k0 + 4);
    float4 a2 = *(const float4*)(Arow + k0 + 8);
    float4 a3 = *(const float4*)(Arow + k0 + 12);
    ush8 b0 = *(const ush8*)(Brow + k0);
    ush8 b1 = *(const ush8*)(Brow + k0 + 8);
    ush8 ap0, ap1;
    ap0[0] = f2bf(a0.x); ap0[1] = f2bf(a0.y); ap0[2] = f2bf(a0.z); ap0[3] = f2bf(a0.w);
    ap0[4] = f2bf(a1.x); ap0[5] = f2bf(a1.y); ap0[6] = f2bf(a1.z); ap0[7] = f2bf(a1.w);
    ap1[0] = f2bf(a2.x); ap1[1] = f2bf(a2.y); ap1[2] = f2bf(a2.z); ap1[3] = f2bf(a2.w);
    ap1[4] = f2bf(a3.x); ap1[5] = f2bf(a3.y); ap1[6] = f2bf(a3.z); ap1[7] = f2bf(a3.w);
    *(ush8*)&As[sr][sc] = ap0;
    *(ush8*)&As[sr][sc + 8] = ap1;
    *(ush8*)&Bs[sr][sc] = b0;
    *(ush8*)&Bs[sr][sc + 8] = b1;
    __syncthreads();
#pragma unroll
    for (int kk = 0; kk < 64; kk += 32) {
      short8 af0 = *(const short8*)&As[wr + fr][kk + fk];
      short8 af1 = *(const short8*)&As[wr + 16 + fr][kk + fk];
      short8 bf0 = *(const short8*)&Bs[wc + fr][kk + fk];
      short8 bf1 = *(const short8*)&Bs[wc + 16 + fr][kk + fk];
      acc00 = __builtin_amdgcn_mfma_f32_16x16x32_bf16(af0, bf0, acc00, 0, 0, 0);
      acc01 = __builtin_amdgcn_mfma_f32_16x16x32_bf16(af0, bf1, acc01, 0, 0, 0);
      acc10 = __builtin_amdgcn_mfma_f32_16x16x32_bf16(af1, bf0, acc10, 0, 0, 0);
      acc11 = __builtin_amdgcn_mfma_f32_16x16x32_bf16(af1, bf1, acc11, 0, 0, 0);
    }
    __syncthreads();
  }
#pragma unroll
  for (int mi = 0; mi < 2; mi++) {
#pragma unroll
    for (int ni = 0; ni < 2; ni++) {
      f32x4 av = (mi == 0) ? ((ni == 0) ? acc00 : acc01) : ((ni == 0) ? acc10 : acc11);
      int col = bn + wc + ni * 16 + fr;
      float bv = bias ? bias[col] : 0.f;
#pragma unroll
      for (int r = 0; r < 4; r++) {
        int row = bm + wr + mi * 16 + (lane >> 4) * 4 + r;
        float v2 = av[r] + bv;
        if (relu) v2 = fmaxf(v2, 0.f);
        C[(size_t)row * ldc + col] = v2;
      }
    }
  }
}

// ---------------- 4. rotate/translate points to global
__global__ __launch_bounds__(128) void pointxform(
    const float* __restrict__ proj, const float* __restrict__ rot,
    const float* __restrict__ trans, float* __restrict__ qp,
    float* __restrict__ kp, float* __restrict__ vp) {
  int bn = blockIdx.x;
  int t = threadIdx.x;
  __shared__ float R[9];
  __shared__ float T[3];
  if (t < 9) R[t] = rot[bn * 9 + t];
  if (t < 3) T[t] = trans[bn * 3 + t];
  __syncthreads();
  if (t < 96) {
    int which = t >> 5;
    int pt = t & 31;
    const float* src = proj + (size_t)bn * PROJC + 384 + which * 96 + pt * 3;
    float c0 = src[0], c1 = src[1], c2 = src[2];
    float* dst = (which == 0 ? qp : (which == 1 ? kp : vp)) + (size_t)bn * 96 + pt * 3;
#pragma unroll
    for (int r = 0; r < 3; r++)
      dst[r] = c0 * R[0 * 3 + r] + c1 * R[1 * 3 + r] + c2 * R[2 * 3 + r] + T[r];
  }
}

// ---------------- 5. scalar+point logits, Lsp[bi][j][h] (contiguous per row)
__global__ __launch_bounds__(512) void logits_sp(
    const float* __restrict__ proj, const float* __restrict__ qp,
    const float* __restrict__ kp, const float* __restrict__ pw,
    const float* __restrict__ b_pair, float* __restrict__ Lsp) {
  int bi = blockIdx.x;
  int b = bi >> 9, i = bi & 511;
  int t = threadIdx.x;
  __shared__ float qs[128], qpi[96], wh[8], bp[8];
  size_t bn_i = (size_t)b * 512 + i;
  if (t < 32) *(float4*)&qs[t * 4] = *(const float4*)&proj[bn_i * PROJC + t * 4];
  else if (t < 56) *(float4*)&qpi[(t - 32) * 4] = *(const float4*)&qp[bn_i * 96 + (t - 32) * 4];
  else if (t < 64) {
    wh[t - 56] = 0.5f * log1pf(__expf(pw[t - 56])) * POINT_SCALE;
    bp[t - 56] = b_pair[t - 56] * PAIR_SCALE;
  }
  __syncthreads();
  int j = t;
  const float* kr = proj + ((size_t)b * 512 + j) * PROJC + 128;
  const float* kpr = kp + ((size_t)b * 512 + j) * 96;
  float lv[8];
#pragma unroll
  for (int h = 0; h < 8; h++) {
    float s = 0.f;
#pragma unroll
    for (int dd = 0; dd < 16; dd++) s += qs[h * 16 + dd] * kr[h * 16 + dd];
    float d2 = 0.f;
#pragma unroll
    for (int p = 0; p < 12; p++) {
      float df = qpi[h * 12 + p] - kpr[h * 12 + p];
      d2 += df * df;
    }
    lv[h] = s * SCALAR_SCALE - wh[h] * d2 + bp[h];
  }
  float* dst = Lsp + ((size_t)bi * 512 + j) * 8;
  float4 o0 = make_float4(lv[0], lv[1], lv[2], lv[3]);
  float4 o1 = make_float4(lv[4], lv[5], lv[6], lv[7]);
  *(float4*)&dst[0] = o0;
  *(float4*)&dst[4] = o1;
}

// ---------------- 6. fused flash attention over pair (pipelined, 32-j tiles)
__global__ __launch_bounds__(256) void flash_pair(
    const float* __restrict__ pair, const float* __restrict__ Wpair,
    const float* __restrict__ Lsp, const float* __restrict__ proj,
    const float* __restrict__ vp, const float* __restrict__ rot,
    const float* __restrict__ trans, float* __restrict__ concat) {
  int bi = blockIdx.x;
  int b = bi >> 9;
  int t = threadIdx.x;
  __shared__ float tile[32 * 128];   // swizzled pair tile (16 KB)
  __shared__ float Lt[32][9];        // Lsp tile [j][h]
  __shared__ float Pl[8][36];        // P [h][j]
  __shared__ float xw[4][8], xl[4][8];
  __shared__ float rsh[8], ish[8];
  __shared__ float pg[96], plcl[96];
  __shared__ float Rm[9], Tv[3];
  if (t < 9) Rm[t] = rot[bi * 9 + t];
  if (t < 3) Tv[t] = trans[bi * 3 + t];

  const int w = t >> 6, lane = t & 63;
  const int jq = t >> 4, dp = t & 15;
  const int d = t & 127, half = t >> 7;
  const int c = d >> 2, dlow = d & 3;
  const int hs = (t >> 4) & 7;        // head for out_s (t<128)
  const int ixg = t - 128;
  const int hv = (ixg >= 0 && ixg < 96) ? ixg / 12 : 0;

  // Wpair slice for this lane's 8 d's
  float wv[8][8];
#pragma unroll
  for (int q = 0; q < 8; q++) {
    float4 u0 = *(const float4*)&Wpair[(dp * 8 + q) * 8];
    float4 u1 = *(const float4*)&Wpair[(dp * 8 + q) * 8 + 4];
    wv[q][0] = u0.x; wv[q][1] = u0.y; wv[q][2] = u0.z; wv[q][3] = u0.w;
    wv[q][4] = u1.x; wv[q][5] = u1.y; wv[q][6] = u1.z; wv[q][7] = u1.w;
  }

  float m_run[8], l_run[8], accp[8];
#pragma unroll
  for (int h = 0; h < 8; h++) { m_run[h] = -1e30f; l_run[h] = 0.f; accp[h] = 0.f; }
  float accs = 0.f, accg = 0.f;

  const float* pbase = pair + (size_t)bi * 512 * 128;
  const float* LspB = Lsp + (size_t)bi * 4096;
  const float* vsbase = proj + (size_t)b * 512 * PROJC + 256 + t;
  const float* vpbase = vp + (size_t)b * 512 * 96 + ixg;

  // ---- prologue: stage tile 0 (swizzled) + Lt 0
#pragma unroll
  for (int it = 0; it < 4; it++) {
    int f4 = it * 256 + t, j = f4 >> 5, cc = f4 & 31;
    float4 v = *(const float4*)&pbase[(size_t)j * 128 + ((cc ^ (j & 7)) << 2)];
    *(float4*)&tile[f4 * 4] = v;
  }
  Lt[t >> 3][t & 7] = LspB[t];
  __syncthreads();

  for (int kt = 0; kt < 16; kt++) {
    // ---- A: issue prefetch (tile kt+1) to registers — in flight all body
    float4 pr0, pr1, pr2, pr3;
    float lspr = 0.f;
    if (kt < 15) {
      const float* nsrc = pbase + (size_t)(kt + 1) * 32 * 128;
      {
        int f4 = t, j = f4 >> 5, cc = f4 & 31;
        pr0 = *(const float4*)&nsrc[(size_t)j * 128 + ((cc ^ (j & 7)) << 2)];
      }
      {
        int f4 = 256 + t, j = f4 >> 5, cc = f4 & 31;
        pr1 = *(const float4*)&nsrc[(size_t)j * 128 + ((cc ^ (j & 7)) << 2)];
      }
      {
        int f4 = 512 + t, j = f4 >> 5, cc = f4 & 31;
        pr2 = *(const float4*)&nsrc[(size_t)j * 128 + ((cc ^ (j & 7)) << 2)];
      }
      {
        int f4 = 768 + t, j = f4 >> 5, cc = f4 & 31;
        pr3 = *(const float4*)&nsrc[(size_t)j * 128 + ((cc ^ (j & 7)) << 2)];
      }
      lspr = LspB[(kt + 1) * 256 + t];
    }

    // ---- B: pair logits from LDS tile kt, reg-resident result
    float L0[8], L1[8];
#pragma unroll
    for (int jj = 0; jj < 2; jj++) {
      int j = jq + jj * 16;
      int cb = j * 128, msk = j & 7;
      f32x4 pa = *(const f32x4*)&tile[cb + (((dp * 2) ^ msk) << 2)];
      f32x4 pb = *(const f32x4*)&tile[cb + (((dp * 2 + 1) ^ msk) << 2)];
      float p[8] = {pa[0], pa[1], pa[2], pa[3], pb[0], pb[1], pb[2], pb[3]};
      float part[8];
#pragma unroll
      for (int h = 0; h < 8; h++) part[h] = 0.f;
#pragma unroll
      for (int q = 0; q < 8; q++)
#pragma unroll
        for (int h = 0; h < 8; h++) part[h] += p[q] * wv[q][h];
#pragma unroll
      for (int h = 0; h < 8; h++) {
        part[h] += __shfl_xor(part[h], 1);
        part[h] += __shfl_xor(part[h], 2);
        part[h] += __shfl_xor(part[h], 4);
        part[h] += __shfl_xor(part[h], 8);
        float lv = part[h] * PAIR_SCALE + Lt[j][h];
        if (jj == 0) L0[h] = lv; else L1[h] = lv;
      }
    }
    // wave-level max partial (all lanes hold result)
    float wm[8];
#pragma unroll
    for (int h = 0; h < 8; h++) {
      float v = fmaxf(L0[h], L1[h]);
      v = fmaxf(v, __shfl_xor(v, 16));
      v = fmaxf(v, __shfl_xor(v, 32));
      wm[h] = v;
    }
#pragma unroll
    for (int h = 0; h < 8; h++) if (lane == h) xw[w][h] = wm[h];
    __syncthreads();  // B1

    // ---- C: m update, P, Pl write, l partial
    float r_[8];
#pragma unroll
    for (int h = 0; h < 8; h++) {
      float mn = fmaxf(fmaxf(xw[0][h], xw[1][h]), fmaxf(xw[2][h], xw[3][h]));
      mn = fmaxf(m_run[h], mn);
      r_[h] = __expf(m_run[h] - mn);
      m_run[h] = mn;
    }
#pragma unroll
    for (int h = 0; h < 8; h++) if (t == h) rsh[h] = r_[h];
    float P0[8], P1[8];
#pragma unroll
    for (int h = 0; h < 8; h++) {
      P0[h] = __expf(L0[h] - m_run[h]);
      P1[h] = __expf(L1[h] - m_run[h]);
    }
    if (dp == 0) {
#pragma unroll
      for (int h = 0; h < 8; h++) {
        Pl[h][jq] = P0[h];
        Pl[h][jq + 16] = P1[h];
      }
    }
#pragma unroll
    for (int h = 0; h < 8; h++) {
      float ls = P0[h] + P1[h];
      ls += __shfl_xor(ls, 16);
      ls += __shfl_xor(ls, 32);
      if (lane == h) xl[w][h] = ls;
    }
    __syncthreads();  // B2

    // ---- D: accumulate (tile kt + Pl consumed here)
#pragma unroll
    for (int h = 0; h < 8; h++)
      l_run[h] = l_run[h] * r_[h] + (xl[0][h] + xl[1][h] + xl[2][h] + xl[3][h]);
#pragma unroll
    for (int h = 0; h < 8; h++) accp[h] *= r_[h];
#pragma unroll
    for (int jg = 0; jg < 4; jg++) {
      int j = half * 16 + jg * 4;
      float q0 = tile[(j + 0) * 128 + (((c ^ ((j + 0) & 7)) << 2) | dlow)];
      float q1 = tile[(j + 1) * 128 + (((c ^ ((j + 1) & 7)) << 2) | dlow)];
      float q2 = tile[(j + 2) * 128 + (((c ^ ((j + 2) & 7)) << 2) | dlow)];
      float q3 = tile[(j + 3) * 128 + (((c ^ ((j + 3) & 7)) << 2) | dlow)];
#pragma unroll
      for (int h = 0; h < 8; h++) {
        float4 pw4 = *(const float4*)&Pl[h][j];
        accp[h] += pw4.x * q0 + pw4.y * q1 + pw4.z * q2 + pw4.w * q3;
      }
    }
    if (t < 128) {
      float rs = rsh[hs];
      float s0 = 0.f, s1 = 0.f;
      const float* vb = vsbase + (size_t)kt * 32 * PROJC;
#pragma unroll 8
      for (int j = 0; j < 32; j += 2) {
        s0 += Pl[hs][j] * vb[(size_t)j * PROJC];
        s1 += Pl[hs][j + 1] * vb[(size_t)(j + 1) * PROJC];
      }
      accs = accs * rs + s0 + s1;
    } else if (t < 224) {
      float rs = rsh[hv];
      float s0 = 0.f, s1 = 0.f;
      const float* vb = vpbase + (size_t)kt * 32 * 96;
#pragma unroll 8
      for (int j = 0; j < 32; j += 2) {
        s0 += Pl[hv][j] * vb[(size_t)j * 96];
        s1 += Pl[hv][j + 1] * vb[(size_t)(j + 1) * 96];
      }
      accg = accg * rs + s0 + s1;
    }
    __syncthreads();  // B3

    // ---- E: write prefetched tile kt+1 (vmcnt waits land here, overlapped)
    if (kt < 15) {
      *(float4*)&tile[(size_t)t * 4] = pr0;
      *(float4*)&tile[(size_t)(256 + t) * 4] = pr1;
      *(float4*)&tile[(size_t)(512 + t) * 4] = pr2;
      *(float4*)&tile[(size_t)(768 + t) * 4] = pr3;
      Lt[t >> 3][t & 7] = lspr;
    }
    __syncthreads();  // B4
  }

  // ---- epilogue
  float invl[8];
#pragma unroll
  for (int h = 0; h < 8; h++) invl[h] = 1.f / l_run[h];
#pragma unroll
  for (int h = 0; h < 8; h++) if (t == h) ish[h] = invl[h];
  float* crow = concat + (size_t)bi * CONCATC;
  if (half) {
#pragma unroll
    for (int h = 0; h < 8; h++) tile[d * 8 + h] = accp[h];
  }
  __syncthreads();
  if (!half) {
#pragma unroll
    for (int h = 0; h < 8; h++)
      crow[256 + h * 128 + d] = (accp[h] + tile[d * 8 + h]) * invl[h];
  }
  if (t < 128) crow[t] = accs * ish[hs];
  if (t >= 128 && t < 224) pg[ixg] = accg * ish[hv];
  __syncthreads();
  if (t < 96) {
    int hp = t / 3, cc2 = t % 3;
    float v = 0.f;
#pragma unroll
    for (int r = 0; r < 3; r++) v += Rm[cc2 * 3 + r] * (pg[hp * 3 + r] - Tv[r]);
    plcl[t] = v;
    crow[128 + t] = v;
  }
  __syncthreads();
  if (t < 32) {
    float v0 = plcl[t * 3], v1 = plcl[t * 3 + 1], v2 = plcl[t * 3 + 2];
    crow[224 + t] = sqrtf(v0 * v0 + v1 * v1 + v2 * v2 + 1e-8f);
  }
}

// ---------------- 7. layernorm (+residual)
__global__ __launch_bounds__(256) void ln_kernel(
    const float* __restrict__ in, const float* __restrict__ res,
    const float* __restrict__ g, const float* __restrict__ bt,
    float* __restrict__ out) {
  int row = blockIdx.x;
  int t = threadIdx.x;
  __shared__ float red[8];
  size_t base = (size_t)row * 512;
  float v0 = in[base + t] + res[base + t];
  float v1 = in[base + t + 256] + res[base + t + 256];
  int wid = t >> 6, lane = t & 63;
  float s = wred_sum(v0 + v1);
  if (lane == 0) red[wid] = s;
  __syncthreads();
  float mean = (red[0] + red[1] + red[2] + red[3]) * (1.f / 512.f);
  float d0 = v0 - mean, d1 = v1 - mean;
  float q = wred_sum(d0 * d0 + d1 * d1);
  __syncthreads();
  if (lane == 0) red[wid] = q;
  __syncthreads();
  float var = (red[0] + red[1] + red[2] + red[3]) * (1.f / 512.f);
  float rs = rsqrtf(var + 1e-3f);
  out[base + t] = d0 * rs * g[t] + bt[t];
  out[base + t + 256] = d1 * rs * g[t + 256] + bt[t + 256];
}

// ---------------------------------------------------------------- launcher
extern "C" void kernel_launch(void* const* d_in, const int* in_sizes, int n_in,
                              void* d_out, int out_size, void* d_ws, size_t ws_size,
                              hipStream_t stream) {
  const float* x      = (const float*)d_in[0];
  const float* pair   = (const float*)d_in[1];
  const float* rot    = (const float*)d_in[2];
  const float* trans  = (const float*)d_in[3];
  const float* Wqs    = (const float*)d_in[4];
  const float* Wks    = (const float*)d_in[5];
  const float* Wvs    = (const float*)d_in[6];
  const float* Wqp    = (const float*)d_in[7];
  const float* Wkp    = (const float*)d_in[8];
  const float* Wvp    = (const float*)d_in[9];
  const float* pw     = (const float*)d_in[10];
  const float* Wpair  = (const float*)d_in[11];
  const float* b_pair = (const float*)d_in[12];
  const float* Wo     = (const float*)d_in[13];
  const float* bo     = (const float*)d_in[14];
  const float* ln1g   = (const float*)d_in[15];
  const float* ln1b   = (const float*)d_in[16];
  const float* ln2g   = (const float*)d_in[17];
  const float* ln2b   = (const float*)d_in[18];
  const float* ffw1   = (const float*)d_in[19];
  const float* ffb1   = (const float*)d_in[20];
  const float* ffw2   = (const float*)d_in[21];
  const float* ffb2   = (const float*)d_in[22];
  const float* ffw3   = (const float*)d_in[23];
  const float* ffb3   = (const float*)d_in[24];
  float* out = (float*)d_out;

  float* ws = (float*)d_ws;
  unsigned short* Wcat_t = (unsigned short*)ws; ws += (704 * 512) / 2;
  unsigned short* Wo_t   = (unsigned short*)ws; ws += (512 * 1280) / 2;
  unsigned short* ff1_t  = (unsigned short*)ws; ws += (512 * 512) / 2;
  unsigned short* ff2_t  = (unsigned short*)ws; ws += (512 * 512) / 2;
  unsigned short* ff3_t  = (unsigned short*)ws; ws += (512 * 512) / 2;
  float* proj   = ws; ws += (size_t)RR * PROJC;
  float* qp     = ws; ws += RR * 96;
  float* kp     = ws; ws += RR * 96;
  float* vp     = ws; ws += RR * 96;
  float* Lsp    = ws; ws += (size_t)RR * 512 * 8;
  float* concat = ws; ws += (size_t)RR * CONCATC;
  float* tmp1   = ws; ws += RR * 512;
  float* a      = ws; ws += RR * 512;
  float* h1     = ws; ws += RR * 512;
  float* h2     = ws; ws += RR * 512;
  float* f      = ws; ws += RR * 512;

  dim3 b256(256);
  hipLaunchKernelGGL(gather_wcat_t, dim3(704), b256, 0, stream,
                     Wqs, Wks, Wvs, Wqp, Wkp, Wvp, Wcat_t);
  hipLaunchKernelGGL(transp_cvt4, dim3(16, 40, 4), b256, 0, stream,
                     Wo, ffw1, ffw2, ffw3, Wo_t, ff1_t, ff2_t, ff3_t);
  hipLaunchKernelGGL(gemm_bf16, dim3(11, 16), b256, 0, stream,
                     x, 512, Wcat_t, 512, proj, PROJC, (const float*)nullptr, 0);
  hipLaunchKernelGGL(pointxform, dim3(RR), dim3(128), 0, stream,
                     proj, rot, trans, qp, kp, vp);
  hipLaunchKernelGGL(logits_sp, dim3(RR), dim3(512), 0, stream,
                     proj, qp, kp, pw, b_pair, Lsp);
  hipLaunchKernelGGL(flash_pair, dim3(RR), b256, 0, stream,
                     pair, Wpair, Lsp, proj, vp, rot, trans, concat);
  hipLaunchKernelGGL(gemm_bf16, dim3(8, 16), b256, 0, stream,
                     concat, CONCATC, Wo_t, 1280, tmp1, 512, bo, 0);
  hipLaunchKernelGGL(ln_kernel, dim3(RR), b256, 0, stream, tmp1, x, ln1g, ln1b, a);
  hipLaunchKernelGGL(gemm_bf16, dim3(8, 16), b256, 0, stream,
                     a, 512, ff1_t, 512, h1, 512, ffb1, 1);
  hipLaunchKernelGGL(gemm_bf16, dim3(8, 16), b256, 0, stream,
                     h1, 512, ff2_t, 512, h2, 512, ffb2, 1);
  hipLaunchKernelGGL(gemm_bf16, dim3(8, 16), b256, 0, stream,
                     h2, 512, ff3_t, 512, f, 512, ffb3, 0);
  hipLaunchKernelGGL(ln_kernel, dim3(RR), b256, 0, stream, f, a, ln2g, ln2b, out);
}

// Round 5
// 305.204 us; speedup vs baseline: 2.3615x; 2.3615x over previous
//
#include <hip/hip_runtime.h>
#include <math.h>

#define Bb 2
#define Nn 512
#define RR 1024
#define HH 8
#define PROJC 704
#define CONCATC 1280
#define PSTRIDE 1280   // per-(bi,split) partial: 1024 accp + 128 accs + 96 accg + 8 m + 8 l + pad

#define SCALAR_SCALE 0.14433756729740643f
#define POINT_SCALE  0.13608276348795434f
#define PAIR_SCALE   0.5773502691896258f

typedef __attribute__((ext_vector_type(4))) float f32x4;
typedef __attribute__((ext_vector_type(8))) short short8;
typedef __attribute__((ext_vector_type(8))) unsigned short ush8;

__device__ __forceinline__ float wred_sum(float v) {
#pragma unroll
  for (int o = 1; o < 64; o <<= 1) v += __shfl_xor(v, o);
  return v;
}
__device__ __forceinline__ unsigned short f2bf(float f) {
  unsigned int u = __float_as_uint(f);
  unsigned int r = (u + 0x7FFFu + ((u >> 16) & 1u)) >> 16;
  return (unsigned short)r;
}

// ---------------- 1. gather + transpose + cvt Wcat_t bf16 [704][512]
__global__ __launch_bounds__(256) void gather_wcat_t(
    const float* __restrict__ Wqs, const float* __restrict__ Wks,
    const float* __restrict__ Wvs, const float* __restrict__ Wqp,
    const float* __restrict__ Wkp, const float* __restrict__ Wvp,
    unsigned short* __restrict__ Wt) {
  int c = blockIdx.x;
  for (int k = threadIdx.x; k < 512; k += 256) {
    float val = 0.f;
    if (c < 128)      val = Wqs[k * 128 + c];
    else if (c < 256) val = Wks[k * 128 + c - 128];
    else if (c < 384) val = Wvs[k * 128 + c - 256];
    else if (c < 480) val = Wqp[k * 96 + c - 384];
    else if (c < 576) val = Wkp[k * 96 + c - 480];
    else if (c < 672) val = Wvp[k * 96 + c - 576];
    Wt[(size_t)c * 512 + k] = f2bf(val);
  }
}

// ---------------- 2. transpose+cvt 4 weights: f32 [K][512] -> bf16 [512][K]
__global__ __launch_bounds__(256) void transp_cvt4(
    const float* __restrict__ w0, const float* __restrict__ w1,
    const float* __restrict__ w2, const float* __restrict__ w3,
    unsigned short* __restrict__ o0, unsigned short* __restrict__ o1,
    unsigned short* __restrict__ o2, unsigned short* __restrict__ o3) {
  int z = blockIdx.z;
  const float* in = (z == 0) ? w0 : (z == 1) ? w1 : (z == 2) ? w2 : w3;
  unsigned short* out = (z == 0) ? o0 : (z == 1) ? o1 : (z == 2) ? o2 : o3;
  int K = (z == 0) ? 1280 : 512;
  int k0 = blockIdx.y * 32, n0 = blockIdx.x * 32;
  if (k0 >= K) return;
  __shared__ float tile[32][33];
  int t = threadIdx.x;
  int r = t >> 3, cq = (t & 7) * 4;
  float4 v = *(const float4*)&in[(size_t)(k0 + r) * 512 + n0 + cq];
  tile[r][cq] = v.x; tile[r][cq + 1] = v.y; tile[r][cq + 2] = v.z; tile[r][cq + 3] = v.w;
  __syncthreads();
  ushort4 o4;
  o4.x = f2bf(tile[cq + 0][r]);
  o4.y = f2bf(tile[cq + 1][r]);
  o4.z = f2bf(tile[cq + 2][r]);
  o4.w = f2bf(tile[cq + 3][r]);
  *(ushort4*)&out[(size_t)(n0 + r) * K + k0 + cq] = o4;
}

// ---------------- 3. bf16 MFMA GEMM (64x64 tile)
__global__ __launch_bounds__(256) void gemm_bf16(
    const float* __restrict__ A, int lda,
    const unsigned short* __restrict__ Bt, int K,
    float* __restrict__ C, int ldc,
    const float* __restrict__ bias, int relu) {
  __shared__ unsigned short As[64][72];
  __shared__ unsigned short Bs[64][72];
  int t = threadIdx.x;
  int lane = t & 63, w = t >> 6;
  int wr = (w >> 1) * 32, wc = (w & 1) * 32;
  int fr = lane & 15, fk = (lane >> 4) * 8;
  f32x4 zero = {0.f, 0.f, 0.f, 0.f};
  f32x4 acc00 = zero, acc01 = zero, acc10 = zero, acc11 = zero;
  int sr = t >> 2, sc = (t & 3) * 16;
  int bm = blockIdx.y * 64, bn = blockIdx.x * 64;
  const float* Arow = A + (size_t)(bm + sr) * lda + sc;
  const unsigned short* Brow = Bt + (size_t)(bn + sr) * K + sc;
  for (int k0 = 0; k0 < K; k0 += 64) {
    float4 a0 = *(const float4*)(Arow + k0);
    float4 a1 = *(const float4*)(Arow + k0 + 4);
    float4 a2 = *(const float4*)(Arow + k0 + 8);
    float4 a3 = *(const float4*)(Arow + k0 + 12);
    ush8 b0 = *(const ush8*)(Brow + k0);
    ush8 b1 = *(const ush8*)(Brow + k0 + 8);
    ush8 ap0, ap1;
    ap0[0] = f2bf(a0.x); ap0[1] = f2bf(a0.y); ap0[2] = f2bf(a0.z); ap0[3] = f2bf(a0.w);
    ap0[4] = f2bf(a1.x); ap0[5] = f2bf(a1.y); ap0[6] = f2bf(a1.z); ap0[7] = f2bf(a1.w);
    ap1[0] = f2bf(a2.x); ap1[1] = f2bf(a2.y); ap1[2] = f2bf(a2.z); ap1[3] = f2bf(a2.w);
    ap1[4] = f2bf(a3.x); ap1[5] = f2bf(a3.y); ap1[6] = f2bf(a3.z); ap1[7] = f2bf(a3.w);
    *(ush8*)&As[sr][sc] = ap0;
    *(ush8*)&As[sr][sc + 8] = ap1;
    *(ush8*)&Bs[sr][sc] = b0;
    *(ush8*)&Bs[sr][sc + 8] = b1;
    __syncthreads();
#pragma unroll
    for (int kk = 0; kk < 64; kk += 32) {
      short8 af0 = *(const short8*)&As[wr + fr][kk + fk];
      short8 af1 = *(const short8*)&As[wr + 16 + fr][kk + fk];
      short8 bf0 = *(const short8*)&Bs[wc + fr][kk + fk];
      short8 bf1 = *(const short8*)&Bs[wc + 16 + fr][kk + fk];
      acc00 = __builtin_amdgcn_mfma_f32_16x16x32_bf16(af0, bf0, acc00, 0, 0, 0);
      acc01 = __builtin_amdgcn_mfma_f32_16x16x32_bf16(af0, bf1, acc01, 0, 0, 0);
      acc10 = __builtin_amdgcn_mfma_f32_16x16x32_bf16(af1, bf0, acc10, 0, 0, 0);
      acc11 = __builtin_amdgcn_mfma_f32_16x16x32_bf16(af1, bf1, acc11, 0, 0, 0);
    }
    __syncthreads();
  }
#pragma unroll
  for (int mi = 0; mi < 2; mi++) {
#pragma unroll
    for (int ni = 0; ni < 2; ni++) {
      f32x4 av = (mi == 0) ? ((ni == 0) ? acc00 : acc01) : ((ni == 0) ? acc10 : acc11);
      int col = bn + wc + ni * 16 + fr;
      float bv = bias ? bias[col] : 0.f;
#pragma unroll
      for (int r = 0; r < 4; r++) {
        int row = bm + wr + mi * 16 + (lane >> 4) * 4 + r;
        float v2 = av[r] + bv;
        if (relu) v2 = fmaxf(v2, 0.f);
        C[(size_t)row * ldc + col] = v2;
      }
    }
  }
}

// ---------------- 4. rotate/translate points to global
__global__ __launch_bounds__(128) void pointxform(
    const float* __restrict__ proj, const float* __restrict__ rot,
    const float* __restrict__ trans, float* __restrict__ qp,
    float* __restrict__ kp, float* __restrict__ vp) {
  int bn = blockIdx.x;
  int t = threadIdx.x;
  __shared__ float R[9];
  __shared__ float T[3];
  if (t < 9) R[t] = rot[bn * 9 + t];
  if (t < 3) T[t] = trans[bn * 3 + t];
  __syncthreads();
  if (t < 96) {
    int which = t >> 5;
    int pt = t & 31;
    const float* src = proj + (size_t)bn * PROJC + 384 + which * 96 + pt * 3;
    float c0 = src[0], c1 = src[1], c2 = src[2];
    float* dst = (which == 0 ? qp : (which == 1 ? kp : vp)) + (size_t)bn * 96 + pt * 3;
#pragma unroll
    for (int r = 0; r < 3; r++)
      dst[r] = c0 * R[0 * 3 + r] + c1 * R[1 * 3 + r] + c2 * R[2 * 3 + r] + T[r];
  }
}

// ---------------- 5. scalar+point logits, Lsp[bi][j][h]
__global__ __launch_bounds__(512) void logits_sp(
    const float* __restrict__ proj, const float* __restrict__ qp,
    const float* __restrict__ kp, const float* __restrict__ pw,
    const float* __restrict__ b_pair, float* __restrict__ Lsp) {
  int bi = blockIdx.x;
  int b = bi >> 9, i = bi & 511;
  int t = threadIdx.x;
  __shared__ float qs[128], qpi[96], wh[8], bp[8];
  size_t bn_i = (size_t)b * 512 + i;
  if (t < 32) *(float4*)&qs[t * 4] = *(const float4*)&proj[bn_i * PROJC + t * 4];
  else if (t < 56) *(float4*)&qpi[(t - 32) * 4] = *(const float4*)&qp[bn_i * 96 + (t - 32) * 4];
  else if (t < 64) {
    wh[t - 56] = 0.5f * log1pf(__expf(pw[t - 56])) * POINT_SCALE;
    bp[t - 56] = b_pair[t - 56] * PAIR_SCALE;
  }
  __syncthreads();
  int j = t;
  const float* kr = proj + ((size_t)b * 512 + j) * PROJC + 128;
  const float* kpr = kp + ((size_t)b * 512 + j) * 96;
  float lv[8];
#pragma unroll
  for (int h = 0; h < 8; h++) {
    float s = 0.f;
#pragma unroll
    for (int dd = 0; dd < 16; dd++) s += qs[h * 16 + dd] * kr[h * 16 + dd];
    float d2 = 0.f;
#pragma unroll
    for (int p = 0; p < 12; p++) {
      float df = qpi[h * 12 + p] - kpr[h * 12 + p];
      d2 += df * df;
    }
    lv[h] = s * SCALAR_SCALE - wh[h] * d2 + bp[h];
  }
  float* dst = Lsp + ((size_t)bi * 512 + j) * 8;
  *(float4*)&dst[0] = make_float4(lv[0], lv[1], lv[2], lv[3]);
  *(float4*)&dst[4] = make_float4(lv[4], lv[5], lv[6], lv[7]);
}

// ---------------- 6. split-j fused pass over pair (one HBM stream of pair)
// grid (1024, 4): block = (bi, chunk of 128 j). Writes partials.
__global__ __launch_bounds__(256) void flash_split(
    const float* __restrict__ pair, const float* __restrict__ Wpair,
    const float* __restrict__ Lsp, const float* __restrict__ proj,
    const float* __restrict__ vp, float* __restrict__ pbuf) {
  int bi = blockIdx.x, c = blockIdx.y;
  int b = bi >> 9;
  int t = threadIdx.x;
  __shared__ float L[128][9];
  __shared__ float P[8][132];
  __shared__ float msh[8], lsh[8];
  __shared__ float racc[128][8];

  const float* pbase = pair + ((size_t)bi * 512 + (size_t)c * 128) * 128;
  // init L[j][h] from Lsp (coalesced 1024 floats)
  {
    const float* LspC = Lsp + ((size_t)bi * 512 + (size_t)c * 128) * 8;
    float4 v0 = *(const float4*)&LspC[t * 4];
    int j = t >> 1, h4 = (t & 1) * 4;
    L[j][h4 + 0] = v0.x; L[j][h4 + 1] = v0.y;
    L[j][h4 + 2] = v0.z; L[j][h4 + 3] = v0.w;
  }
  // Wpair slice into regs (live only through phase 1)
  const int jq = t >> 4, dp = t & 15;
  float wv[8][8];
#pragma unroll
  for (int q = 0; q < 8; q++) {
    float4 u0 = *(const float4*)&Wpair[(dp * 8 + q) * 8];
    float4 u1 = *(const float4*)&Wpair[(dp * 8 + q) * 8 + 4];
    wv[q][0] = u0.x; wv[q][1] = u0.y; wv[q][2] = u0.z; wv[q][3] = u0.w;
    wv[q][4] = u1.x; wv[q][5] = u1.y; wv[q][6] = u1.z; wv[q][7] = u1.w;
  }
  __syncthreads();

  // ---- phase 1: pair logits (direct global, coalesced)
#pragma unroll 2
  for (int it = 0; it < 8; it++) {
    int j = it * 16 + jq;
    const float* pr = pbase + (size_t)j * 128 + dp * 8;
    float4 p0 = *(const float4*)pr;
    float4 p1 = *(const float4*)(pr + 4);
    float p[8] = {p0.x, p0.y, p0.z, p0.w, p1.x, p1.y, p1.z, p1.w};
    float part[8];
#pragma unroll
    for (int h = 0; h < 8; h++) part[h] = 0.f;
#pragma unroll
    for (int q = 0; q < 8; q++)
#pragma unroll
      for (int h = 0; h < 8; h++) part[h] += p[q] * wv[q][h];
#pragma unroll
    for (int h = 0; h < 8; h++) {
      part[h] += __shfl_xor(part[h], 1);
      part[h] += __shfl_xor(part[h], 2);
      part[h] += __shfl_xor(part[h], 4);
      part[h] += __shfl_xor(part[h], 8);
    }
    if (dp == 0) {
#pragma unroll
      for (int h = 0; h < 8; h++) L[j][h] += part[h] * PAIR_SCALE;
    }
  }
  __syncthreads();

  // ---- local max per head
  if (t < 64) {
    int h = t >> 3, q = t & 7;
    float m = -1e30f;
#pragma unroll
    for (int k = 0; k < 16; k++) m = fmaxf(m, L[q * 16 + k][h]);
    m = fmaxf(m, __shfl_xor(m, 1));
    m = fmaxf(m, __shfl_xor(m, 2));
    m = fmaxf(m, __shfl_xor(m, 4));
    if (q == 0) msh[h] = m;
  }
  __syncthreads();
  // ---- P = exp(L - m)
  {
    int j = t >> 1, h4 = (t & 1) * 4;
#pragma unroll
    for (int k = 0; k < 4; k++) P[h4 + k][j] = __expf(L[j][h4 + k] - msh[h4 + k]);
  }
  __syncthreads();
  // ---- local l per head
  if (t < 64) {
    int h = t >> 3, q = t & 7;
    float s = 0.f;
#pragma unroll
    for (int k = 0; k < 16; k++) s += P[h][q * 16 + k];
    s += __shfl_xor(s, 1);
    s += __shfl_xor(s, 2);
    s += __shfl_xor(s, 4);
    if (q == 0) lsh[h] = s;
  }

  // ---- phase 3: out_pair partial (column reads hit L2)
  const int d = t & 127, half = t >> 7;
  float accp[8];
#pragma unroll
  for (int h = 0; h < 8; h++) accp[h] = 0.f;
  {
    const float* colp = pbase + (size_t)(half * 64) * 128 + d;
#pragma unroll 2
    for (int jg = 0; jg < 16; jg++) {
      int j0 = half * 64 + jg * 4;
      float q0 = colp[(size_t)(jg * 4 + 0) * 128];
      float q1 = colp[(size_t)(jg * 4 + 1) * 128];
      float q2 = colp[(size_t)(jg * 4 + 2) * 128];
      float q3 = colp[(size_t)(jg * 4 + 3) * 128];
#pragma unroll
      for (int h = 0; h < 8; h++) {
        float4 pw4 = *(const float4*)&P[h][j0];
        accp[h] += pw4.x * q0 + pw4.y * q1 + pw4.z * q2 + pw4.w * q3;
      }
    }
  }
  // ---- phase 4: out_s / out_pg partials (L2/L3-resident V)
  float accs = 0.f, accg = 0.f;
  if (t < 128) {
    int hs = t >> 4;
    const float* vb = proj + (size_t)(b * 512 + c * 128) * PROJC + 256 + t;
#pragma unroll 4
    for (int j = 0; j < 128; j++) accs += P[hs][j] * vb[(size_t)j * PROJC];
  } else if (t < 224) {
    int ix = t - 128, hv = ix / 12;
    const float* vb = vp + (size_t)(b * 512 + c * 128) * 96 + ix;
#pragma unroll 4
    for (int j = 0; j < 128; j++) accg += P[hv][j] * vb[(size_t)j * 96];
  }

  // ---- write partials
  if (half) {
#pragma unroll
    for (int h = 0; h < 8; h++) racc[d][h] = accp[h];
  }
  __syncthreads();
  float* po = pbuf + ((size_t)bi * 4 + c) * PSTRIDE;
  if (!half) {
#pragma unroll
    for (int h = 0; h < 8; h++) po[h * 128 + d] = accp[h] + racc[d][h];
  }
  if (t < 128) po[1024 + t] = accs;
  else if (t < 224) po[1152 + (t - 128)] = accg;
  if (t < 8) { po[1248 + t] = msh[t]; po[1256 + t] = lsh[t]; }
}

// ---------------- 7. combine splits + frame transform + norms -> concat
__global__ __launch_bounds__(256) void combine_splits(
    const float* __restrict__ pbuf, const float* __restrict__ rot,
    const float* __restrict__ trans, float* __restrict__ concat) {
  int bi = blockIdx.x;
  int t = threadIdx.x;
  __shared__ float sc[4][8];
  __shared__ float pg[96], plcl[96];
  __shared__ float Rm[9], Tv[3];
  if (t < 9) Rm[t] = rot[bi * 9 + t];
  if (t < 3) Tv[t] = trans[bi * 3 + t];
  const float* pb = pbuf + (size_t)bi * 4 * PSTRIDE;
  if (t < 8) {
    float m0 = pb[0 * PSTRIDE + 1248 + t], m1 = pb[1 * PSTRIDE + 1248 + t];
    float m2 = pb[2 * PSTRIDE + 1248 + t], m3 = pb[3 * PSTRIDE + 1248 + t];
    float M = fmaxf(fmaxf(m0, m1), fmaxf(m2, m3));
    float s0 = __expf(m0 - M), s1 = __expf(m1 - M);
    float s2 = __expf(m2 - M), s3 = __expf(m3 - M);
    float denom = pb[0 * PSTRIDE + 1256 + t] * s0 + pb[1 * PSTRIDE + 1256 + t] * s1 +
                  pb[2 * PSTRIDE + 1256 + t] * s2 + pb[3 * PSTRIDE + 1256 + t] * s3;
    float inv = 1.f / denom;
    sc[0][t] = s0 * inv; sc[1][t] = s1 * inv;
    sc[2][t] = s2 * inv; sc[3][t] = s3 * inv;
  }
  __syncthreads();
  float* crow = concat + (size_t)bi * CONCATC;
#pragma unroll
  for (int q = 0; q < 4; q++) {
    int idx = q * 256 + t;
    int h = idx >> 7;
    float v = pb[0 * PSTRIDE + idx] * sc[0][h] + pb[1 * PSTRIDE + idx] * sc[1][h] +
              pb[2 * PSTRIDE + idx] * sc[2][h] + pb[3 * PSTRIDE + idx] * sc[3][h];
    crow[256 + idx] = v;
  }
  if (t < 128) {
    int h = t >> 4;
    float v = pb[0 * PSTRIDE + 1024 + t] * sc[0][h] + pb[1 * PSTRIDE + 1024 + t] * sc[1][h] +
              pb[2 * PSTRIDE + 1024 + t] * sc[2][h] + pb[3 * PSTRIDE + 1024 + t] * sc[3][h];
    crow[t] = v;
  } else if (t < 224) {
    int ix = t - 128, h = ix / 12;
    float v = pb[0 * PSTRIDE + 1152 + ix] * sc[0][h] + pb[1 * PSTRIDE + 1152 + ix] * sc[1][h] +
              pb[2 * PSTRIDE + 1152 + ix] * sc[2][h] + pb[3 * PSTRIDE + 1152 + ix] * sc[3][h];
    pg[ix] = v;
  }
  __syncthreads();
  if (t < 96) {
    int hp = t / 3, cc = t % 3;
    float v = 0.f;
#pragma unroll
    for (int r = 0; r < 3; r++) v += Rm[cc * 3 + r] * (pg[hp * 3 + r] - Tv[r]);
    plcl[t] = v;
    crow[128 + t] = v;
  }
  __syncthreads();
  if (t < 32) {
    float v0 = plcl[t * 3], v1 = plcl[t * 3 + 1], v2 = plcl[t * 3 + 2];
    crow[224 + t] = sqrtf(v0 * v0 + v1 * v1 + v2 * v2 + 1e-8f);
  }
}

// ---------------- 8. layernorm (+residual)
__global__ __launch_bounds__(256) void ln_kernel(
    const float* __restrict__ in, const float* __restrict__ res,
    const float* __restrict__ g, const float* __restrict__ bt,
    float* __restrict__ out) {
  int row = blockIdx.x;
  int t = threadIdx.x;
  __shared__ float red[8];
  size_t base = (size_t)row * 512;
  float v0 = in[base + t] + res[base + t];
  float v1 = in[base + t + 256] + res[base + t + 256];
  int wid = t >> 6, lane = t & 63;
  float s = wred_sum(v0 + v1);
  if (lane == 0) red[wid] = s;
  __syncthreads();
  float mean = (red[0] + red[1] + red[2] + red[3]) * (1.f / 512.f);
  float d0 = v0 - mean, d1 = v1 - mean;
  float q = wred_sum(d0 * d0 + d1 * d1);
  __syncthreads();
  if (lane == 0) red[wid] = q;
  __syncthreads();
  float var = (red[0] + red[1] + red[2] + red[3]) * (1.f / 512.f);
  float rs = rsqrtf(var + 1e-3f);
  out[base + t] = d0 * rs * g[t] + bt[t];
  out[base + t + 256] = d1 * rs * g[t + 256] + bt[t + 256];
}

// ---------------------------------------------------------------- launcher
extern "C" void kernel_launch(void* const* d_in, const int* in_sizes, int n_in,
                              void* d_out, int out_size, void* d_ws, size_t ws_size,
                              hipStream_t stream) {
  const float* x      = (const float*)d_in[0];
  const float* pair   = (const float*)d_in[1];
  const float* rot    = (const float*)d_in[2];
  const float* trans  = (const float*)d_in[3];
  const float* Wqs    = (const float*)d_in[4];
  const float* Wks    = (const float*)d_in[5];
  const float* Wvs    = (const float*)d_in[6];
  const float* Wqp    = (const float*)d_in[7];
  const float* Wkp    = (const float*)d_in[8];
  const float* Wvp    = (const float*)d_in[9];
  const float* pw     = (const float*)d_in[10];
  const float* Wpair  = (const float*)d_in[11];
  const float* b_pair = (const float*)d_in[12];
  const float* Wo     = (const float*)d_in[13];
  const float* bo     = (const float*)d_in[14];
  const float* ln1g   = (const float*)d_in[15];
  const float* ln1b   = (const float*)d_in[16];
  const float* ln2g   = (const float*)d_in[17];
  const float* ln2b   = (const float*)d_in[18];
  const float* ffw1   = (const float*)d_in[19];
  const float* ffb1   = (const float*)d_in[20];
  const float* ffw2   = (const float*)d_in[21];
  const float* ffb2   = (const float*)d_in[22];
  const float* ffw3   = (const float*)d_in[23];
  const float* ffb3   = (const float*)d_in[24];
  float* out = (float*)d_out;

  float* ws = (float*)d_ws;
  unsigned short* Wcat_t = (unsigned short*)ws; ws += (704 * 512) / 2;
  unsigned short* Wo_t   = (unsigned short*)ws; ws += (512 * 1280) / 2;
  unsigned short* ff1_t  = (unsigned short*)ws; ws += (512 * 512) / 2;
  unsigned short* ff2_t  = (unsigned short*)ws; ws += (512 * 512) / 2;
  unsigned short* ff3_t  = (unsigned short*)ws; ws += (512 * 512) / 2;
  float* proj   = ws; ws += (size_t)RR * PROJC;
  float* qp     = ws; ws += RR * 96;
  float* kp     = ws; ws += RR * 96;
  float* vp     = ws; ws += RR * 96;
  float* Lsp    = ws; ws += (size_t)RR * 512 * 8;
  float* pbuf   = ws; ws += (size_t)RR * 4 * PSTRIDE;
  float* concat = ws; ws += (size_t)RR * CONCATC;
  float* tmp1   = ws; ws += RR * 512;
  float* a      = ws; ws += RR * 512;
  float* h1     = ws; ws += RR * 512;
  float* h2     = ws; ws += RR * 512;
  float* f      = ws; ws += RR * 512;

  dim3 b256(256);
  hipLaunchKernelGGL(gather_wcat_t, dim3(704), b256, 0, stream,
                     Wqs, Wks, Wvs, Wqp, Wkp, Wvp, Wcat_t);
  hipLaunchKernelGGL(transp_cvt4, dim3(16, 40, 4), b256, 0, stream,
                     Wo, ffw1, ffw2, ffw3, Wo_t, ff1_t, ff2_t, ff3_t);
  hipLaunchKernelGGL(gemm_bf16, dim3(11, 16), b256, 0, stream,
                     x, 512, Wcat_t, 512, proj, PROJC, (const float*)nullptr, 0);
  hipLaunchKernelGGL(pointxform, dim3(RR), dim3(128), 0, stream,
                     proj, rot, trans, qp, kp, vp);
  hipLaunchKernelGGL(logits_sp, dim3(RR), dim3(512), 0, stream,
                     proj, qp, kp, pw, b_pair, Lsp);
  hipLaunchKernelGGL(flash_split, dim3(RR, 4), b256, 0, stream,
                     pair, Wpair, Lsp, proj, vp, pbuf);
  hipLaunchKernelGGL(combine_splits, dim3(RR), b256, 0, stream,
                     pbuf, rot, trans, concat);
  hipLaunchKernelGGL(gemm_bf16, dim3(8, 16), b256, 0, stream,
                     concat, CONCATC, Wo_t, 1280, tmp1, 512, bo, 0);
  hipLaunchKernelGGL(ln_kernel, dim3(RR), b256, 0, stream, tmp1, x, ln1g, ln1b, a);
  hipLaunchKernelGGL(gemm_bf16, dim3(8, 16), b256, 0, stream,
                     a, 512, ff1_t, 512, h1, 512, ffb1, 1);
  hipLaunchKernelGGL(gemm_bf16, dim3(8, 16), b256, 0, stream,
                     h1, 512, ff2_t, 512, h2, 512, ffb2, 1);
  hipLaunchKernelGGL(gemm_bf16, dim3(8, 16), b256, 0, stream,
                     h2, 512, ff3_t, 512, f, 512, ffb3, 0);
  hipLaunchKernelGGL(ln_kernel, dim3(RR), b256, 0, stream, f, a, ln2g, ln2b, out);
}